// Round 3
// baseline (200.953 us; speedup 1.0000x reference)
//
#include <hip/hip_runtime.h>
#include <math.h>

#define NB 8
#define NQ 100
#define NCP1 3
#define NC 2
#define HIN 128
#define WIN 128
#define HOUT 512
#define WOUT 512
#define QSTR (HIN * WIN)

#if __has_builtin(__builtin_amdgcn_exp2f)
#define EXP2F(x) __builtin_amdgcn_exp2f(x)
#else
#define EXP2F(x) exp2f(x)
#endif
#if __has_builtin(__builtin_amdgcn_rcpf)
#define RCPF(x) __builtin_amdgcn_rcpf(x)
#else
#define RCPF(x) (1.0f / (x))
#endif

__device__ __forceinline__ float2 f2(float x, float y) { return make_float2(x, y); }
__device__ __forceinline__ float2 fma2(float2 a, float2 b, float2 c) {
  return make_float2(fmaf(a.x, b.x, c.x), fmaf(a.y, b.y, c.y));
}
__device__ __forceinline__ float2 mul2(float2 a, float2 b) {
  return make_float2(a.x * b.x, a.y * b.y);
}
__device__ __forceinline__ float2 add1_2(float2 a) {
  return make_float2(a.x + 1.0f, a.y + 1.0f);
}

// Block = (b,k): 4 output rows y=4k..4k+3.  Thread (r=tid>>6, c=tid&63) owns
// output row y=4k+r, cols 8c..8c+7  <-  input rows {rlo,rhi} x cols 2c-1..2c+2
// (clamped).  Loads: per row 1 dwordx2 (cols 2c,2c+1) + 2 scalars, all with
// wave-uniform SGPR base (per-q scalar advance) + constant voffsets -> zero
// per-q address VALU.  float2 math throughout for v_pk_* codegen.  Depth-4
// software pipeline.  One barrier total.
__global__ __launch_bounds__(256, 4)
void m2f_fused(const float* __restrict__ cls,
               const float* __restrict__ masks,
               float* __restrict__ out) {
  const int k   = blockIdx.x;   // 0..127
  const int b   = blockIdx.y;   // 0..7
  const int tid = threadIdx.x;  // 0..255

  __shared__ float2 pqd0[NQ];   // (p0,p0) per q — pk-ready broadcast pairs
  __shared__ float2 pqd1[NQ];   // (p1,p1) per q

  // ---- inline class softmax (keep first NC of NCP1) ----
  if (tid < NQ) {
    const float* cl = cls + (b * NQ + tid) * NCP1;
    float a0 = cl[0], a1 = cl[1], a2 = cl[2];
    float mx = fmaxf(a0, fmaxf(a1, a2));
    const float L2E = 1.4426950408889634f;
    float e0 = EXP2F((a0 - mx) * L2E);
    float e1 = EXP2F((a1 - mx) * L2E);
    float e2 = EXP2F((a2 - mx) * L2E);
    float inv = RCPF(e0 + e1 + e2);
    pqd0[tid] = f2(e0 * inv, e0 * inv);
    pqd1[tid] = f2(e1 * inv, e1 * inv);
  }
  __syncthreads();   // the only barrier

  const int r = tid >> 6;       // output row phase 0..3  (y = 4k+r)
  const int c = tid & 63;       // col group: x = 8c..8c+7

  // clamped input rows + vertical weights (scaled by -log2e so that
  // sigmoid(x) = rcp(1 + exp2(v)), v = -log2e * x)
  const int rlo = (r < 2) ? (k > 0 ? k - 1 : 0) : k;
  const int rhi = (r < 2) ? k : (k < HIN - 1 ? k + 1 : HIN - 1);
  const float NL2E = -1.4426950408889634f;
  const float wlo = ((r == 0) ? 0.375f : (r == 1) ? 0.125f
                   : (r == 2) ? 0.875f : 0.625f) * NL2E;
  const float whi = ((r == 0) ? 0.625f : (r == 1) ? 0.875f
                   : (r == 2) ? 0.125f : 0.375f) * NL2E;
  const float2 wlo2 = f2(wlo, wlo);
  const float2 whi2 = f2(whi, whi);

  // clamped input cols (element offsets; per-thread constants)
  const int cm = (c > 0) ? 2 * c - 1 : 0;
  const int c0 = 2 * c;                      // pair (2c, 2c+1) always in range
  const int cp = (c < 63) ? 2 * c + 2 : WIN - 1;
  const int oAm = rlo * WIN + cm, oA0 = rlo * WIN + c0, oAp = rlo * WIN + cp;
  const int oBm = rhi * WIN + cm, oB0 = rhi * WIN + c0, oBp = rhi * WIN + cp;

  const float* __restrict__ base = masks + (size_t)b * NQ * QSTR;  // uniform

  // accumulators: 8 px x 2 classes as float2 pairs
  float2 a0p[4], a1p[4];
#pragma unroll
  for (int j = 0; j < 4; ++j) { a0p[j] = f2(0.f, 0.f); a1p[j] = f2(0.f, 0.f); }

  // pipeline registers: 4 sets x 8 floats
  float  am0, ap0, bm0, bp0;  float2 a010, b010;
  float  am1, ap1, bm1, bp1;  float2 a011, b011;
  float  am2, ap2, bm2, bp2;  float2 a012, b012;
  float  am3, ap3, bm3, bp3;  float2 a013, b013;

#define LOADSET(S, qq)                                                 \
  do {                                                                 \
    const float* mq = base + (size_t)(qq) * QSTR;  /* uniform SGPR */  \
    am##S = mq[oAm]; a01##S = *(const float2*)(mq + oA0); ap##S = mq[oAp]; \
    bm##S = mq[oBm]; b01##S = *(const float2*)(mq + oB0); bp##S = mq[oBp]; \
  } while (0)

#define COMPUTE(S, qq)                                                 \
  do {                                                                 \
    const float2 pd0 = pqd0[qq];                                       \
    const float2 pd1 = pqd1[qq];                                       \
    /* vertical lerp (pre-scaled by -log2e) */                         \
    float  tm  = fmaf(wlo, am##S, whi * bm##S);                        \
    float  tp  = fmaf(wlo, ap##S, whi * bp##S);                        \
    float2 t01 = fma2(wlo2, a01##S, mul2(whi2, b01##S));               \
    /* horizontal lerp, diff form */                                   \
    float dm  = tm - t01.x;                                            \
    float d01 = t01.y - t01.x;                                         \
    float dp  = tp - t01.y;                                            \
    float v0 = fmaf(0.375f, dm,  t01.x);                               \
    float v1 = fmaf(0.125f, dm,  t01.x);                               \
    float v2 = fmaf(0.125f, d01, t01.x);                               \
    float v3 = fmaf(0.375f, d01, t01.x);                               \
    float v4 = fmaf(0.625f, d01, t01.x);                               \
    float v5 = fmaf(0.875f, d01, t01.x);                               \
    float v6 = fmaf(0.125f, dp,  t01.y);                               \
    float v7 = fmaf(0.375f, dp,  t01.y);                               \
    /* sigmoid = rcp(1 + exp2(v)) */                                   \
    float2 u01 = add1_2(f2(EXP2F(v0), EXP2F(v1)));                     \
    float2 u23 = add1_2(f2(EXP2F(v2), EXP2F(v3)));                     \
    float2 u45 = add1_2(f2(EXP2F(v4), EXP2F(v5)));                     \
    float2 u67 = add1_2(f2(EXP2F(v6), EXP2F(v7)));                     \
    float2 s01 = f2(RCPF(u01.x), RCPF(u01.y));                         \
    float2 s23 = f2(RCPF(u23.x), RCPF(u23.y));                         \
    float2 s45 = f2(RCPF(u45.x), RCPF(u45.y));                         \
    float2 s67 = f2(RCPF(u67.x), RCPF(u67.y));                         \
    a0p[0] = fma2(pd0, s01, a0p[0]);  a1p[0] = fma2(pd1, s01, a1p[0]); \
    a0p[1] = fma2(pd0, s23, a0p[1]);  a1p[1] = fma2(pd1, s23, a1p[1]); \
    a0p[2] = fma2(pd0, s45, a0p[2]);  a1p[2] = fma2(pd1, s45, a1p[2]); \
    a0p[3] = fma2(pd0, s67, a0p[3]);  a1p[3] = fma2(pd1, s67, a1p[3]); \
  } while (0)

  LOADSET(0, 0); LOADSET(1, 1); LOADSET(2, 2); LOADSET(3, 3);

  for (int q = 0; q < NQ; q += 4) {
    COMPUTE(0, q);     if (q + 4 < NQ) LOADSET(0, q + 4);
    COMPUTE(1, q + 1); if (q + 5 < NQ) LOADSET(1, q + 5);
    COMPUTE(2, q + 2); if (q + 6 < NQ) LOADSET(2, q + 6);
    COMPUTE(3, q + 3); if (q + 7 < NQ) LOADSET(3, q + 7);
  }

  // ---- stores: row y=4k+r, cols 8c..8c+7, both classes ----
  const int y  = 4 * k + r;
  const int x0 = 8 * c;
  float* o0 = out + (((size_t)b * NC + 0) * HOUT + y) * WOUT + x0;
  float* o1 = out + (((size_t)b * NC + 1) * HOUT + y) * WOUT + x0;
  *(float4*)o0       = make_float4(a0p[0].x, a0p[0].y, a0p[1].x, a0p[1].y);
  *(float4*)(o0 + 4) = make_float4(a0p[2].x, a0p[2].y, a0p[3].x, a0p[3].y);
  *(float4*)o1       = make_float4(a1p[0].x, a1p[0].y, a1p[1].x, a1p[1].y);
  *(float4*)(o1 + 4) = make_float4(a1p[2].x, a1p[2].y, a1p[3].x, a1p[3].y);
}

extern "C" void kernel_launch(void* const* d_in, const int* in_sizes, int n_in,
                              void* d_out, int out_size, void* d_ws, size_t ws_size,
                              hipStream_t stream) {
  const float* cls   = (const float*)d_in[0];   // [8,100,3] fp32
  const float* masks = (const float*)d_in[1];   // [8,100,128,128] fp32
  float* out = (float*)d_out;                   // [8,2,512,512] fp32
  dim3 grid(HIN, NB);   // 128 k-groups x 8 batches = 1024 blocks
  m2f_fused<<<grid, 256, 0, stream>>>(cls, masks, out);
}

// Round 4
// 162.637 us; speedup vs baseline: 1.2356x; 1.2356x over previous
//
#include <hip/hip_runtime.h>
#include <math.h>

#define NB 8
#define NQ 100
#define NCP1 3
#define NC 2
#define HIN 128
#define WIN 128
#define HOUT 512
#define WOUT 512
#define QSTR (HIN * WIN)

typedef float v2f __attribute__((ext_vector_type(2)));

#if __has_builtin(__builtin_amdgcn_exp2f)
#define EXP2F(x) __builtin_amdgcn_exp2f(x)
#else
#define EXP2F(x) exp2f(x)
#endif
#if __has_builtin(__builtin_amdgcn_rcpf)
#define RCPF(x) __builtin_amdgcn_rcpf(x)
#else
#define RCPF(x) (1.0f / (x))
#endif

__device__ __forceinline__ v2f mk2(float x, float y) { v2f r; r.x = x; r.y = y; return r; }

// Block = (b,k): output rows 4k..4k+3.  Thread (half = tid>>7, c = tid&127)
// owns 2 output rows (phases half*2, half*2+1) x 4 cols (4c..4c+3), i.e. 8 px
// from 6 input floats per q: cols {c-1,c,c+1} x rows {ra,rb} (all clamped at
// setup).  The two row-phases ride the two lanes of v2f -> v_pk_* codegen.
// One v_rcp serves all 8 sigmoids via a product tree.  Depth-2 pipeline,
// unroll-2, one barrier total.  (Depth-4 spilled in R3: WRITE_SIZE +14MB.)
__global__ __launch_bounds__(256, 4)
void m2f_fused(const float* __restrict__ cls,
               const float* __restrict__ masks,
               float* __restrict__ out) {
  const int k   = blockIdx.x;   // 0..127
  const int b   = blockIdx.y;   // 0..7
  const int tid = threadIdx.x;  // 0..255

  __shared__ v2f pq[NQ];        // (p_class0, p_class1) per q

  // ---- inline class softmax (keep first NC of NCP1) ----
  if (tid < NQ) {
    const float* cl = cls + (b * NQ + tid) * NCP1;
    float a0 = cl[0], a1 = cl[1], a2 = cl[2];
    float mx = fmaxf(a0, fmaxf(a1, a2));
    const float L2E = 1.4426950408889634f;
    float e0 = EXP2F((a0 - mx) * L2E);
    float e1 = EXP2F((a1 - mx) * L2E);
    float e2 = EXP2F((a2 - mx) * L2E);
    float inv = RCPF(e0 + e1 + e2);
    pq[tid] = mk2(e0 * inv, e1 * inv);
  }
  __syncthreads();   // the only barrier

  const int half = tid >> 7;    // 0: rows 4k,4k+1   1: rows 4k+2,4k+3
  const int c    = tid & 127;   // cols 4c..4c+3

  // clamped input rows for this half
  const int ra = half ? k : (k > 0 ? k - 1 : 0);
  const int rb = half ? (k < HIN - 1 ? k + 1 : HIN - 1) : k;

  // vertical weights per phase pair, pre-scaled by -log2(e) so that
  // sigmoid(x) = rcp(1 + exp2(v)), v = -log2e * x.
  // phases (0,1): 0.375/0.625, 0.125/0.875 ; phases (2,3): 0.875/0.125, 0.625/0.375
  const float NL2E = -1.4426950408889634f;
  const v2f wlo2 = half ? mk2(0.875f * NL2E, 0.625f * NL2E)
                        : mk2(0.375f * NL2E, 0.125f * NL2E);
  const v2f whi2 = half ? mk2(0.125f * NL2E, 0.375f * NL2E)
                        : mk2(0.625f * NL2E, 0.875f * NL2E);

  // clamped input cols (per-thread-constant element offsets)
  const int cm = (c > 0) ? c - 1 : 0;
  const int cp = (c < WIN - 1) ? c + 1 : WIN - 1;
  const int oAm = ra * WIN + cm, oA0 = ra * WIN + c, oAp = ra * WIN + cp;
  const int oBm = rb * WIN + cm, oB0 = rb * WIN + c, oBp = rb * WIN + cp;

  const float* __restrict__ base = masks + (size_t)b * NQ * QSTR;  // uniform

  v2f accA[4], accB[4];   // [col], lanes = (class0, class1)
#pragma unroll
  for (int j = 0; j < 4; ++j) { accA[j] = mk2(0.f, 0.f); accB[j] = mk2(0.f, 0.f); }

  // depth-2 pipeline registers (6 floats each)
  float am0, a00, ap0, bm0, b00, bp0;
  float am1, a01, ap1, bm1, b01, bp1;

#define LOADSET(S, qq)                                                   \
  do {                                                                   \
    const float* mq = base + (size_t)(qq) * QSTR; /* uniform SGPR */     \
    am##S = mq[oAm]; a0##S = mq[oA0]; ap##S = mq[oAp];                   \
    bm##S = mq[oBm]; b0##S = mq[oB0]; bp##S = mq[oBp];                   \
  } while (0)

#define COMPUTE(S, qq)                                                   \
  do {                                                                   \
    const v2f pd = pq[qq];                                               \
    /* vertical lerp, both phases in v2f lanes (scaled by -log2e) */     \
    v2f tm = wlo2 * am##S + whi2 * bm##S;                                \
    v2f t0 = wlo2 * a0##S + whi2 * b0##S;                                \
    v2f tp = wlo2 * ap##S + whi2 * bp##S;                                \
    /* horizontal lerp, diff form: cols s=0..3 */                        \
    v2f dm = tm - t0;                                                    \
    v2f dp = tp - t0;                                                    \
    v2f v0 = t0 + 0.375f * dm;                                           \
    v2f v1 = t0 + 0.125f * dm;                                           \
    v2f v2_ = t0 + 0.125f * dp;                                          \
    v2f v3_ = t0 + 0.375f * dp;                                          \
    /* denominators d = 1 + exp2(v) (lane .x = row A, .y = row B) */     \
    v2f dv0 = mk2(EXP2F(v0.x),  EXP2F(v0.y))  + 1.0f;                    \
    v2f dv1 = mk2(EXP2F(v1.x),  EXP2F(v1.y))  + 1.0f;                    \
    v2f dv2 = mk2(EXP2F(v2_.x), EXP2F(v2_.y)) + 1.0f;                    \
    v2f dv3 = mk2(EXP2F(v3_.x), EXP2F(v3_.y)) + 1.0f;                    \
    /* one rcp for all 8 sigmoids via product tree */                    \
    float d0 = dv0.x, d1 = dv0.y, d2 = dv1.x, d3 = dv1.y;                \
    float d4 = dv2.x, d5 = dv2.y, d6 = dv3.x, d7 = dv3.y;                \
    float m0 = d0 * d1, m1 = d2 * d3, m2 = d4 * d5, m3 = d6 * d7;        \
    float n0 = m0 * m1, n1 = m2 * m3;                                    \
    float R  = RCPF(n0 * n1);                                            \
    float rn0 = R * n1, rn1 = R * n0;                                    \
    float rm0 = rn0 * m1, rm1 = rn0 * m0;                                \
    float rm2 = rn1 * m3, rm3 = rn1 * m2;                                \
    float s0 = rm0 * d1, s1 = rm0 * d0;  /* col0: rowA, rowB */          \
    float s2 = rm1 * d3, s3 = rm1 * d2;  /* col1 */                      \
    float s4 = rm2 * d5, s5 = rm2 * d4;  /* col2 */                      \
    float s6 = rm3 * d7, s7 = rm3 * d6;  /* col3 */                      \
    accA[0] += pd * s0;  accB[0] += pd * s1;                             \
    accA[1] += pd * s2;  accB[1] += pd * s3;                             \
    accA[2] += pd * s4;  accB[2] += pd * s5;                             \
    accA[3] += pd * s6;  accB[3] += pd * s7;                             \
  } while (0)

  LOADSET(0, 0);
  LOADSET(1, 1);

  for (int q = 0; q < NQ; q += 2) {
    COMPUTE(0, q);
    if (q + 2 < NQ) LOADSET(0, q + 2);
    COMPUTE(1, q + 1);
    if (q + 3 < NQ) LOADSET(1, q + 3);
  }

  // ---- stores: rows y0=4k+2*half (A) and y0+1 (B), cols 4c..4c+3 ----
  const int y0 = 4 * k + 2 * half;
  const int x0 = 4 * c;
  float* oc0 = out + (((size_t)b * NC + 0) * HOUT + y0) * WOUT + x0;
  float* oc1 = out + (((size_t)b * NC + 1) * HOUT + y0) * WOUT + x0;
  *(float4*)oc0          = make_float4(accA[0].x, accA[1].x, accA[2].x, accA[3].x);
  *(float4*)(oc0 + WOUT) = make_float4(accB[0].x, accB[1].x, accB[2].x, accB[3].x);
  *(float4*)oc1          = make_float4(accA[0].y, accA[1].y, accA[2].y, accA[3].y);
  *(float4*)(oc1 + WOUT) = make_float4(accB[0].y, accB[1].y, accB[2].y, accB[3].y);
}

extern "C" void kernel_launch(void* const* d_in, const int* in_sizes, int n_in,
                              void* d_out, int out_size, void* d_ws, size_t ws_size,
                              hipStream_t stream) {
  const float* cls   = (const float*)d_in[0];   // [8,100,3] fp32
  const float* masks = (const float*)d_in[1];   // [8,100,128,128] fp32
  float* out = (float*)d_out;                   // [8,2,512,512] fp32
  dim3 grid(HIN, NB);   // 128 k-groups x 8 batches = 1024 blocks
  m2f_fused<<<grid, 256, 0, stream>>>(cls, masks, out);
}

// Round 5
// 157.210 us; speedup vs baseline: 1.2782x; 1.0345x over previous
//
#include <hip/hip_runtime.h>
#include <math.h>

#define NB 8
#define NQ 100
#define NCP1 3
#define NC 2
#define HIN 128
#define WIN 128
#define HOUT 512
#define WOUT 512
#define QSTR (HIN * WIN)

#if __has_builtin(__builtin_amdgcn_exp2f)
#define EXP2F(x) __builtin_amdgcn_exp2f(x)
#else
#define EXP2F(x) exp2f(x)
#endif
#if __has_builtin(__builtin_amdgcn_rcpf)
#define RCPF(x) __builtin_amdgcn_rcpf(x)
#else
#define RCPF(x) (1.0f / (x))
#endif

// R5: R2's scalar skeleton (best: 91us, VALUBusy 73%) + scalar rcp product
// tree (1 v_rcp serves 8 sigmoids; R4 showed the tree is right but v2f
// packing movs ate the gain) + diff-form h-lerp.  No vector types in the hot
// loop.  Depth-2 pipeline, unroll-2, SGPR-uniform per-q base, one barrier.
__global__ __launch_bounds__(256, 4)
void m2f_fused(const float* __restrict__ cls,
               const float* __restrict__ masks,
               float* __restrict__ out) {
  const int k   = blockIdx.x;   // 0..127
  const int b   = blockIdx.y;   // 0..7
  const int tid = threadIdx.x;  // 0..255

  __shared__ float pq0[NQ];     // class-0 prob per q
  __shared__ float pq1[NQ];     // class-1 prob per q

  // ---- inline class softmax (keep first NC of NCP1) ----
  if (tid < NQ) {
    const float* cl = cls + (b * NQ + tid) * NCP1;
    float a0 = cl[0], a1 = cl[1], a2 = cl[2];
    float mx = fmaxf(a0, fmaxf(a1, a2));
    const float L2E = 1.4426950408889634f;
    float e0 = EXP2F((a0 - mx) * L2E);
    float e1 = EXP2F((a1 - mx) * L2E);
    float e2 = EXP2F((a2 - mx) * L2E);
    float inv = RCPF(e0 + e1 + e2);
    pq0[tid] = e0 * inv;
    pq1[tid] = e1 * inv;
  }
  __syncthreads();   // the only barrier

  const int h = tid >> 7;       // 0: output rows 4k,4k+1   1: rows 4k+2,4k+3
  const int l = tid & 127;      // cols 4l..4l+3

  // clamped input rows for this half
  const int ra = h ? k : (k > 0 ? k - 1 : 0);
  const int rb = h ? (k < HIN - 1 ? k + 1 : HIN - 1) : k;
  // clamped input cols
  const int lm = (l > 0) ? l - 1 : 0;
  const int lp = (l < WIN - 1) ? l + 1 : WIN - 1;

  // vertical weights, pre-scaled by -log2(e): sigmoid(x) = rcp(1+exp2(v)),
  // v = -log2e * x.  Row phases: h=0 -> (0.375/0.625, 0.125/0.875),
  //                              h=1 -> (0.875/0.125, 0.625/0.375)
  const float NL2E = -1.4426950408889634f;
  const float wA0 = (h ? 0.875f : 0.375f) * NL2E;   // first row, top coeff
  const float wB0 = (h ? 0.125f : 0.625f) * NL2E;
  const float wA1 = (h ? 0.625f : 0.125f) * NL2E;   // second row
  const float wB1 = (h ? 0.375f : 0.875f) * NL2E;

  const float* __restrict__ base = masks + (size_t)b * NQ * QSTR;  // uniform
  const int oAm = ra * WIN + lm, oA0 = ra * WIN + l, oAp = ra * WIN + lp;
  const int oBm = rb * WIN + lm, oB0 = rb * WIN + l, oBp = rb * WIN + lp;

  // accumulators: [row r][col j] for class0 / class1
  float c0r0[4], c0r1[4], c1r0[4], c1r1[4];
#pragma unroll
  for (int j = 0; j < 4; ++j) { c0r0[j] = 0.f; c0r1[j] = 0.f; c1r0[j] = 0.f; c1r1[j] = 0.f; }

  // depth-2 pipeline registers
  float am0, a00, ap0, bm0, b00, bp0;
  float am1, a01, ap1, bm1, b01, bp1;

#define LOADSET(S, qq)                                                   \
  do {                                                                   \
    const float* mq = base + (size_t)(qq) * QSTR; /* uniform SGPR adv */ \
    am##S = mq[oAm]; a0##S = mq[oA0]; ap##S = mq[oAp];                   \
    bm##S = mq[oBm]; b0##S = mq[oB0]; bp##S = mq[oBp];                   \
  } while (0)

#define COMPUTE(S, qq)                                                   \
  do {                                                                   \
    const float p0 = pq0[qq];                                            \
    const float p1 = pq1[qq];                                            \
    /* vertical lerp (pre-scaled by -log2e): 2 rows x 3 cols */          \
    float t0m = fmaf(wA0, am##S, wB0 * bm##S);                           \
    float t00 = fmaf(wA0, a0##S, wB0 * b0##S);                           \
    float t0p = fmaf(wA0, ap##S, wB0 * bp##S);                           \
    float t1m = fmaf(wA1, am##S, wB1 * bm##S);                           \
    float t10 = fmaf(wA1, a0##S, wB1 * b0##S);                           \
    float t1p = fmaf(wA1, ap##S, wB1 * bp##S);                           \
    /* horizontal lerp, diff form: 4 cols per row */                     \
    float dm0 = t0m - t00, dp0 = t0p - t00;                              \
    float dm1 = t1m - t10, dp1 = t1p - t10;                              \
    float v00 = fmaf(0.375f, dm0, t00);                                  \
    float v01 = fmaf(0.125f, dm0, t00);                                  \
    float v02 = fmaf(0.125f, dp0, t00);                                  \
    float v03 = fmaf(0.375f, dp0, t00);                                  \
    float v10 = fmaf(0.375f, dm1, t10);                                  \
    float v11 = fmaf(0.125f, dm1, t10);                                  \
    float v12 = fmaf(0.125f, dp1, t10);                                  \
    float v13 = fmaf(0.375f, dp1, t10);                                  \
    /* denominators d = 1 + exp2(v) */                                   \
    float d0 = EXP2F(v00) + 1.0f;                                        \
    float d1 = EXP2F(v01) + 1.0f;                                        \
    float d2 = EXP2F(v02) + 1.0f;                                        \
    float d3 = EXP2F(v03) + 1.0f;                                        \
    float d4 = EXP2F(v10) + 1.0f;                                        \
    float d5 = EXP2F(v11) + 1.0f;                                        \
    float d6 = EXP2F(v12) + 1.0f;                                        \
    float d7 = EXP2F(v13) + 1.0f;                                        \
    /* one v_rcp for all 8 sigmoids via product tree */                  \
    float m0 = d0 * d1, m1 = d2 * d3, m2 = d4 * d5, m3 = d6 * d7;        \
    float n0 = m0 * m1, n1 = m2 * m3;                                    \
    float R  = RCPF(n0 * n1);                                            \
    float rn0 = R * n1, rn1 = R * n0;                                    \
    float rm0 = rn0 * m1, rm1 = rn0 * m0;                                \
    float rm2 = rn1 * m3, rm3 = rn1 * m2;                                \
    float s00 = rm0 * d1, s01 = rm0 * d0;   /* row0 cols 0,1 */          \
    float s02 = rm1 * d3, s03 = rm1 * d2;   /* row0 cols 2,3 */          \
    float s10 = rm2 * d5, s11 = rm2 * d4;   /* row1 cols 0,1 */          \
    float s12 = rm3 * d7, s13 = rm3 * d6;   /* row1 cols 2,3 */          \
    c0r0[0] = fmaf(p0, s00, c0r0[0]);  c1r0[0] = fmaf(p1, s00, c1r0[0]); \
    c0r0[1] = fmaf(p0, s01, c0r0[1]);  c1r0[1] = fmaf(p1, s01, c1r0[1]); \
    c0r0[2] = fmaf(p0, s02, c0r0[2]);  c1r0[2] = fmaf(p1, s02, c1r0[2]); \
    c0r0[3] = fmaf(p0, s03, c0r0[3]);  c1r0[3] = fmaf(p1, s03, c1r0[3]); \
    c0r1[0] = fmaf(p0, s10, c0r1[0]);  c1r1[0] = fmaf(p1, s10, c1r1[0]); \
    c0r1[1] = fmaf(p0, s11, c0r1[1]);  c1r1[1] = fmaf(p1, s11, c1r1[1]); \
    c0r1[2] = fmaf(p0, s12, c0r1[2]);  c1r1[2] = fmaf(p1, s12, c1r1[2]); \
    c0r1[3] = fmaf(p0, s13, c0r1[3]);  c1r1[3] = fmaf(p1, s13, c1r1[3]); \
  } while (0)

  LOADSET(0, 0);
  LOADSET(1, 1);

  for (int q = 0; q < NQ; q += 2) {
    COMPUTE(0, q);
    if (q + 2 < NQ) LOADSET(0, q + 2);
    COMPUTE(1, q + 1);
    if (q + 3 < NQ) LOADSET(1, q + 3);
  }

  // ---- stores: rows y0=4k+2h, y0+1; cols 4l..4l+3; both classes ----
  const int y0 = 4 * k + 2 * h;
  const int x0 = 4 * l;
  float* o0 = out + (((size_t)b * NC + 0) * HOUT + y0) * WOUT + x0;
  float* o1 = out + (((size_t)b * NC + 1) * HOUT + y0) * WOUT + x0;
  *(float4*)o0          = make_float4(c0r0[0], c0r0[1], c0r0[2], c0r0[3]);
  *(float4*)(o0 + WOUT) = make_float4(c0r1[0], c0r1[1], c0r1[2], c0r1[3]);
  *(float4*)o1          = make_float4(c1r0[0], c1r0[1], c1r0[2], c1r0[3]);
  *(float4*)(o1 + WOUT) = make_float4(c1r1[0], c1r1[1], c1r1[2], c1r1[3]);
}

extern "C" void kernel_launch(void* const* d_in, const int* in_sizes, int n_in,
                              void* d_out, int out_size, void* d_ws, size_t ws_size,
                              hipStream_t stream) {
  const float* cls   = (const float*)d_in[0];   // [8,100,3] fp32
  const float* masks = (const float*)d_in[1];   // [8,100,128,128] fp32
  float* out = (float*)d_out;                   // [8,2,512,512] fp32
  dim3 grid(HIN, NB);   // 128 k-groups x 8 batches = 1024 blocks
  m2f_fused<<<grid, 256, 0, stream>>>(cls, masks, out);
}

// Round 6
// 138.131 us; speedup vs baseline: 1.4548x; 1.1381x over previous
//
#include <hip/hip_runtime.h>
#include <math.h>

#define NB 8
#define NQ 100
#define NCP1 3
#define NC 2
#define HIN 128
#define WIN 128
#define HOUT 512
#define WOUT 512
#define QSTR (HIN * WIN)

#if __has_builtin(__builtin_amdgcn_exp2f)
#define EXP2F(x) __builtin_amdgcn_exp2f(x)
#else
#define EXP2F(x) exp2f(x)
#endif
#if __has_builtin(__builtin_amdgcn_rcpf)
#define RCPF(x) __builtin_amdgcn_rcpf(x)
#else
#define RCPF(x) (1.0f / (x))
#endif

__device__ __forceinline__ float bperm(int byteaddr, float v) {
  return __int_as_float(__builtin_amdgcn_ds_bpermute(byteaddr, __float_as_int(v)));
}

// R6: wave = one full output row (y = 4k + r, r = wave id 0..3); lane owns
// 8 output cols 8c..8c+7, needing input cols 2c-1..2c+2 of rows rlo,rhi.
// Lane loads only cols 2c,2c+1 (one float2 per row -> 2 VMEM/q, coalesced
// 512B/row/wave); neighbor cols come cross-lane via ds_bpermute AFTER the
// vertical lerp (wave covers the full row, so lane 0/63 edges are true image
// edges -> 2 cndmasks).  Depth-4 pipeline (4 VGPR/stage, spill-free — fixes
// R2/R5's ~60% HBM-latency stall; R3's depth-4 spilled at 8 floats/stage).
// Per-pixel rcp (R5 showed the rcp tree's serial join loses to ILP).
__global__ __launch_bounds__(256, 4)
void m2f_fused(const float* __restrict__ cls,
               const float* __restrict__ masks,
               float* __restrict__ out) {
  const int k   = blockIdx.x;   // 0..127
  const int b   = blockIdx.y;   // 0..7
  const int tid = threadIdx.x;  // 0..255

  __shared__ float2 pq[NQ];     // (p_class0, p_class1) per q

  // ---- inline class softmax (keep first NC of NCP1) ----
  if (tid < NQ) {
    const float* cl = cls + (b * NQ + tid) * NCP1;
    float a0 = cl[0], a1 = cl[1], a2 = cl[2];
    float mx = fmaxf(a0, fmaxf(a1, a2));
    const float L2E = 1.4426950408889634f;
    float e0 = EXP2F((a0 - mx) * L2E);
    float e1 = EXP2F((a1 - mx) * L2E);
    float e2 = EXP2F((a2 - mx) * L2E);
    float inv = RCPF(e0 + e1 + e2);
    pq[tid] = make_float2(e0 * inv, e1 * inv);
  }
  __syncthreads();   // the only barrier

  const int r    = tid >> 6;    // wave id = output row phase 0..3 (y = 4k+r)
  const int lane = tid & 63;    // col group: x = 8*lane .. 8*lane+7

  // clamped input rows + vertical weights for this wave's phase.
  // y=4k+r -> v = k + (2r-3)/8:  r=0: 0.375/0.625 on rows k-1/k
  //   r=1: 0.125/0.875 (k-1/k);  r=2: 0.875/0.125 (k/k+1);  r=3: 0.625/0.375
  const int rlo = (r < 2) ? (k > 0 ? k - 1 : 0) : k;
  const int rhi = (r < 2) ? k : (k < HIN - 1 ? k + 1 : HIN - 1);
  const float NL2E = -1.4426950408889634f;   // sigmoid(x)=rcp(1+exp2(-log2e*x))
  const float wlo = ((r == 0) ? 0.375f : (r == 1) ? 0.125f
                   : (r == 2) ? 0.875f : 0.625f) * NL2E;
  const float whi = ((r == 0) ? 0.625f : (r == 1) ? 0.875f
                   : (r == 2) ? 0.125f : 0.375f) * NL2E;

  // per-lane element offsets (constant across q)
  const int oA = rlo * WIN + 2 * lane;
  const int oB = rhi * WIN + 2 * lane;
  const float* __restrict__ base = masks + (size_t)b * NQ * QSTR;  // uniform

  // cross-lane pull addresses (byte = lane*4); out-of-range wraps, fixed by
  // the edge cndmasks below.
  const int addrL = (lane - 1) << 2;
  const int addrR = (lane + 1) << 2;
  const bool edgeL = (lane == 0);
  const bool edgeR = (lane == 63);

  float c0[8], c1[8];
#pragma unroll
  for (int j = 0; j < 8; ++j) { c0[j] = 0.f; c1[j] = 0.f; }

  // depth-4 pipeline: 2 x float2 per stage
  float2 A0, B0, A1, B1, A2, B2, A3, B3;

#define LOADSET(S, qq)                                                    \
  do {                                                                    \
    const float* mq = base + (size_t)(qq) * QSTR; /* uniform SGPR adv */  \
    A##S = *(const float2*)(mq + oA);                                     \
    B##S = *(const float2*)(mq + oB);                                     \
  } while (0)

#define COMPUTE(S, qq)                                                    \
  do {                                                                    \
    const float2 pd = pq[qq];                                             \
    /* vertical lerp (pre-scaled by -log2e) on the 2 owned cols */        \
    float t0 = fmaf(wlo, A##S.x, whi * B##S.x);   /* col 2c   */          \
    float t1 = fmaf(wlo, A##S.y, whi * B##S.y);   /* col 2c+1 */          \
    /* neighbors cross-lane: col 2c-1 = left lane's t1, 2c+2 = right t0 */\
    float tLr = bperm(addrL, t1);                                         \
    float tRr = bperm(addrR, t0);                                         \
    float tL = edgeL ? t0 : tLr;                                          \
    float tR = edgeR ? t1 : tRr;                                          \
    /* horizontal lerp, diff form */                                      \
    float dm = tL - t0, dd = t1 - t0, dp = tR - t1;                       \
    float v0 = fmaf(0.375f, dm, t0);                                      \
    float v1 = fmaf(0.125f, dm, t0);                                      \
    float v2 = fmaf(0.125f, dd, t0);                                      \
    float v3 = fmaf(0.375f, dd, t0);                                      \
    float v4 = fmaf(0.625f, dd, t0);                                      \
    float v5 = fmaf(0.875f, dd, t0);                                      \
    float v6 = fmaf(0.125f, dp, t1);                                      \
    float v7 = fmaf(0.375f, dp, t1);                                      \
    /* sigmoid per pixel (independent chains -> best latency hiding) */   \
    float s0 = RCPF(1.0f + EXP2F(v0));                                    \
    float s1 = RCPF(1.0f + EXP2F(v1));                                    \
    float s2 = RCPF(1.0f + EXP2F(v2));                                    \
    float s3 = RCPF(1.0f + EXP2F(v3));                                    \
    float s4 = RCPF(1.0f + EXP2F(v4));                                    \
    float s5 = RCPF(1.0f + EXP2F(v5));                                    \
    float s6 = RCPF(1.0f + EXP2F(v6));                                    \
    float s7 = RCPF(1.0f + EXP2F(v7));                                    \
    c0[0] = fmaf(pd.x, s0, c0[0]);  c1[0] = fmaf(pd.y, s0, c1[0]);        \
    c0[1] = fmaf(pd.x, s1, c0[1]);  c1[1] = fmaf(pd.y, s1, c1[1]);        \
    c0[2] = fmaf(pd.x, s2, c0[2]);  c1[2] = fmaf(pd.y, s2, c1[2]);        \
    c0[3] = fmaf(pd.x, s3, c0[3]);  c1[3] = fmaf(pd.y, s3, c1[3]);        \
    c0[4] = fmaf(pd.x, s4, c0[4]);  c1[4] = fmaf(pd.y, s4, c1[4]);        \
    c0[5] = fmaf(pd.x, s5, c0[5]);  c1[5] = fmaf(pd.y, s5, c1[5]);        \
    c0[6] = fmaf(pd.x, s6, c0[6]);  c1[6] = fmaf(pd.y, s6, c1[6]);        \
    c0[7] = fmaf(pd.x, s7, c0[7]);  c1[7] = fmaf(pd.y, s7, c1[7]);        \
  } while (0)

  LOADSET(0, 0); LOADSET(1, 1); LOADSET(2, 2); LOADSET(3, 3);

  for (int q = 0; q < NQ; q += 4) {
    COMPUTE(0, q);     if (q + 4 < NQ) LOADSET(0, q + 4);
    COMPUTE(1, q + 1); if (q + 5 < NQ) LOADSET(1, q + 5);
    COMPUTE(2, q + 2); if (q + 6 < NQ) LOADSET(2, q + 6);
    COMPUTE(3, q + 3); if (q + 7 < NQ) LOADSET(3, q + 7);
  }

  // ---- stores: row y = 4k+r, cols 8*lane..8*lane+7, both classes ----
  const int y  = 4 * k + r;
  const int x0 = 8 * lane;
  float* o0 = out + (((size_t)b * NC + 0) * HOUT + y) * WOUT + x0;
  float* o1 = out + (((size_t)b * NC + 1) * HOUT + y) * WOUT + x0;
  *(float4*)o0       = make_float4(c0[0], c0[1], c0[2], c0[3]);
  *(float4*)(o0 + 4) = make_float4(c0[4], c0[5], c0[6], c0[7]);
  *(float4*)o1       = make_float4(c1[0], c1[1], c1[2], c1[3]);
  *(float4*)(o1 + 4) = make_float4(c1[4], c1[5], c1[6], c1[7]);
}

extern "C" void kernel_launch(void* const* d_in, const int* in_sizes, int n_in,
                              void* d_out, int out_size, void* d_ws, size_t ws_size,
                              hipStream_t stream) {
  const float* cls   = (const float*)d_in[0];   // [8,100,3] fp32
  const float* masks = (const float*)d_in[1];   // [8,100,128,128] fp32
  float* out = (float*)d_out;                   // [8,2,512,512] fp32
  dim3 grid(HIN, NB);   // 128 k-groups x 8 batches = 1024 blocks
  m2f_fused<<<grid, 256, 0, stream>>>(cls, masks, out);
}